// Round 1
// 200.781 us; speedup vs baseline: 1.0657x; 1.0657x over previous
//
#include <hip/hip_runtime.h>
#include <hip/hip_bf16.h>
#include <stdint.h>

#define N_NODES 20000
#define N_EDGES 640000
#define FEAT 128
#define CAPD 128   // per-dst list cap; deg ~ Poisson(32), P(>128) ~ 1e-43
#define NPHASE 8   // o-feature slices of 16 (2.56 MB h-slice per phase, L2-resident)

typedef __attribute__((ext_vector_type(8))) short bf16x8;
typedef __attribute__((ext_vector_type(4))) float f32x4;

// ---------- helpers ----------
__device__ __forceinline__ unsigned short bf16r(float f) {
  unsigned a = __float_as_uint(f);
  a = (a + 0x7FFFu + ((a >> 16) & 1u)) >> 16;  // RNE
  return (unsigned short)a;
}

// packed f32x2 -> bf16x2 (v_cvt_pk_bf16_f32), lo in low half
__device__ __forceinline__ unsigned pkbf16(float lo, float hi) {
  __hip_bfloat162 p = __float22bfloat162_rn(make_float2(lo, hi));
  return *reinterpret_cast<unsigned*>(&p);
}

__device__ __forceinline__ void mx2(unsigned u, float& a, float& b) {
  a = fmaxf(a, __uint_as_float(u << 16));
  b = fmaxf(b, __uint_as_float(u & 0xFFFF0000u));
}

#define MX4(v)                                           \
  do {                                                   \
    mx2((v).x, m0, m1); mx2((v).y, m2, m3);              \
    mx2((v).z, m4, m5); mx2((v).w, m6, m7);              \
  } while (0)

// ---------- kernel 1: zero cnt + convert W -> bf16 ([o][f] layout) ----------
__global__ void init_kernel(const float* __restrict__ W,
                            unsigned short* __restrict__ Wbf,
                            int* __restrict__ cnt) {
  int i = blockIdx.x * 256 + threadIdx.x;
  if (i < N_NODES) cnt[i] = 0;
  if (i < FEAT * FEAT / 2) {
    float2 w = ((const float2*)W)[i];
    ((unsigned*)Wbf)[i] = pkbf16(w.x, w.y);
  }
}

// ---------- kernel 2: MFMA GEMM + bias -> h, FUSED per-dst scatter ----------
__global__ __launch_bounds__(256) void gemm_scatter_kernel(
    const float4* __restrict__ x, const unsigned short* __restrict__ Wbf,
    const float* __restrict__ b, uint4* __restrict__ h,
    const int* __restrict__ ei, int* __restrict__ cnt,
    unsigned short* __restrict__ csr) {
  // x-stage: [t][16 n][136 f] bf16 = 17408 B.  h-stage (aliased): [16 n][520] bf16.
  __shared__ __align__(16) unsigned short sm[17408 / 2];
  const int tid = threadIdx.x;
  const int n0 = blockIdx.x * 16;

  // ---- stage x -> LDS bf16 [t][n][f] via v_cvt_pk_bf16_f32 ----
#pragma unroll
  for (int it = 0; it < 4; ++it) {
    int e = tid + it * 256;       // 16 n x 64 f-pairs
    int n = e >> 6, fp = e & 63;  // f = 2*fp
    float4 a = x[(size_t)(n0 + n) * 128 + 2 * fp];
    float4 c = x[(size_t)(n0 + n) * 128 + 2 * fp + 1];
    ((unsigned*)sm)[(0 * 16 + n) * 68 + fp] = pkbf16(a.x, c.x);
    ((unsigned*)sm)[(1 * 16 + n) * 68 + fp] = pkbf16(a.y, c.y);
    ((unsigned*)sm)[(2 * 16 + n) * 68 + fp] = pkbf16(a.z, c.z);
    ((unsigned*)sm)[(3 * 16 + n) * 68 + fp] = pkbf16(a.w, c.w);
  }

  // ---- fused scatter: 512 edges per block into per-dst lists ----
#pragma unroll
  for (int r = 0; r < 2; ++r) {
    int e = blockIdx.x * 512 + r * 256 + tid;
    int src = ei[e];
    int dst = ei[N_EDGES + e];
    int pos = atomicAdd(&cnt[dst], 1);
    if (pos < CAPD) csr[(size_t)dst * CAPD + pos] = (unsigned short)src;
  }

  __syncthreads();

  const int wv = tid >> 6;  // t
  const int l = tid & 63;
  const int col = l & 15;
  const int quad = l >> 4;

  f32x4 acc[8];
#pragma unroll
  for (int os = 0; os < 8; ++os) {
    float bv = b[os * 16 + col];
    acc[os] = (f32x4){bv, bv, bv, bv};
  }

#pragma unroll
  for (int k = 0; k < 4; ++k) {
    bf16x8 af = *(const bf16x8*)&sm[(wv * 16 + col) * 136 + k * 32 + quad * 8];
#pragma unroll
    for (int os = 0; os < 8; ++os) {
      bf16x8 bfv = *(const bf16x8*)&Wbf[(os * 16 + col) * 128 + k * 32 + quad * 8];
      acc[os] = __builtin_amdgcn_mfma_f32_16x16x32_bf16(af, bfv, acc[os], 0, 0, 0);
    }
  }

  __syncthreads();

  // C layout: D[m = quad*4 + r][o = os*16 + col]; h-stage LDS [n][o][t], row 520 shorts.
#pragma unroll
  for (int os = 0; os < 8; ++os) {
#pragma unroll
    for (int r = 0; r < 4; ++r) {
      sm[(quad * 4 + r) * 520 + (os * 16 + col) * 4 + wv] = bf16r(acc[os][r]);
    }
  }
  __syncthreads();

#pragma unroll
  for (int it = 0; it < 4; ++it) {
    int e = tid + it * 256;
    int n = e >> 6, q = e & 63;
    uint4 v = *(const uint4*)&sm[n * 520 + q * 8];
    h[(size_t)(n0 + n) * 64 + q] = v;
  }
}

// ---------- kernel 3: o-phased max aggregation ----------
// blockIdx.y = phase p (16 output features x 4 t = 128 B per node, 2.56 MB slice
// -> L2-resident per XCD). One wave per dst per phase; one wave-load covers
// 8 sources (8 lanes x 16 B each); cross-source reduce via shfl_xor at the end.
__global__ __launch_bounds__(256) void agg_kernel(
    const uint4* __restrict__ h, const int* __restrict__ cnt,
    const unsigned short* __restrict__ csr, float4* __restrict__ out) {
  const int p = blockIdx.y;
  const int w = threadIdx.x >> 6;
  const int lane = threadIdx.x & 63;
  const int n = blockIdx.x * 4 + w;
  const int sub = lane >> 3;  // source slot within a group of 8
  const int oq = lane & 7;    // o-pair slot (2 o x 4 t = 16 B)

  // speculative index reads (csr region always allocated; entries >= deg unused)
  int e1 = (int)csr[(size_t)n * CAPD + lane];
  int e2 = (int)csr[(size_t)n * CAPD + 64 + lane];
  int deg = cnt[n];
  deg = deg > CAPD ? CAPD : deg;
  int idx0 = __shfl(e1, 0);  // valid whenever deg > 0; used to pad tail groups

  float m0 = -INFINITY, m1 = m0, m2 = m0, m3 = m0, m4 = m0, m5 = m0, m6 = m0, m7 = m0;

  const size_t pbase = (size_t)p * 8 + oq;
  int ngrp = (deg + 7) >> 3;
  int g = 0;
  for (; g + 2 <= ngrp; g += 2) {
    int s0 = g * 8 + sub;
    int s1 = s0 + 8;
    int srcA = __shfl((g < 8) ? e1 : e2, s0 & 63);
    int srcB = __shfl((g + 1 < 8) ? e1 : e2, s1 & 63);
    srcA = (s0 < deg) ? srcA : idx0;  // dup of idx0: harmless for max
    srcB = (s1 < deg) ? srcB : idx0;
    uint4 vA = h[(size_t)srcA * 64 + pbase];
    uint4 vB = h[(size_t)srcB * 64 + pbase];
    MX4(vA);
    MX4(vB);
  }
  if (g < ngrp) {
    int s0 = g * 8 + sub;
    int src = __shfl((g < 8) ? e1 : e2, s0 & 63);
    src = (s0 < deg) ? src : idx0;
    uint4 v = h[(size_t)src * 64 + pbase];
    MX4(v);
  }

  // reduce across the 8 source-slots (lane groups of 8): xor 8, 16, 32
#pragma unroll
  for (int d = 8; d <= 32; d <<= 1) {
    m0 = fmaxf(m0, __shfl_xor(m0, d));
    m1 = fmaxf(m1, __shfl_xor(m1, d));
    m2 = fmaxf(m2, __shfl_xor(m2, d));
    m3 = fmaxf(m3, __shfl_xor(m3, d));
    m4 = fmaxf(m4, __shfl_xor(m4, d));
    m5 = fmaxf(m5, __shfl_xor(m5, d));
    m6 = fmaxf(m6, __shfl_xor(m6, d));
    m7 = fmaxf(m7, __shfl_xor(m7, d));
  }
  if (deg == 0) {
    m0 = m1 = m2 = m3 = m4 = m5 = m6 = m7 = 0.0f;
  }
  if (lane < 8) {
    out[(size_t)n * 128 + p * 16 + lane * 2] = make_float4(m0, m1, m2, m3);
    out[(size_t)n * 128 + p * 16 + lane * 2 + 1] = make_float4(m4, m5, m6, m7);
  }
}

// ---------- launcher ----------
extern "C" void kernel_launch(void* const* d_in, const int* in_sizes, int n_in,
                              void* d_out, int out_size, void* d_ws, size_t ws_size,
                              hipStream_t stream) {
  const float* x = (const float*)d_in[0];
  const int* ei = (const int*)d_in[1];
  const float* W = (const float*)d_in[2];
  const float* b = (const float*)d_in[3];
  float* out = (float*)d_out;

  char* ws = (char*)d_ws;
  uint4* h = (uint4*)ws;                                   // 20,480,000 B
  int* cnt = (int*)(ws + 20480000);                        // 20,000 x 4 = 80,000 B
  unsigned short* csr = (unsigned short*)(ws + 20560000);  // 20000*128*2 = 5,120,000 B
  unsigned short* Wbf = (unsigned short*)(ws + 25680000);  // 32,768 B

  init_kernel<<<(N_NODES + 255) / 256, 256, 0, stream>>>(W, Wbf, cnt);
  gemm_scatter_kernel<<<N_NODES / 16, 256, 0, stream>>>((const float4*)x, Wbf, b, h,
                                                        ei, cnt, csr);
  agg_kernel<<<dim3(N_NODES / 4, NPHASE), 256, 0, stream>>>(h, cnt, csr, (float4*)out);
}